// Round 8
// baseline (2113.556 us; speedup 1.0000x reference)
//
#include <hip/hip_runtime.h>
#include <hip/hip_bf16.h>

#define NNODES 100000
#define NEDGES 1600000
#define INF_   128
#define HF     128
#define OUTF   112
#define NLAYERS 4
#define NNETS  3
// feature slicing: 3 nets x 128 = 384 feats = 8 slices x 48
#define NSL    8
#define SLF    48

typedef __attribute__((ext_vector_type(8))) short bf16x8;
typedef __attribute__((ext_vector_type(4))) float f32x4;
typedef unsigned long long u64;
typedef unsigned int u32;

__device__ __forceinline__ float bf2f(short u){
  unsigned x = ((unsigned)(unsigned short)u) << 16;
  return __builtin_bit_cast(float, x);
}
__device__ __forceinline__ unsigned short f2bf(float f){
  unsigned u = __builtin_bit_cast(unsigned, f);
  u += 0x7fffu + ((u >> 16) & 1u);   // RNE
  return (unsigned short)(u >> 16);
}
__device__ __forceinline__ float lo16(u32 q){ return __builtin_bit_cast(float, q << 16); }
__device__ __forceinline__ float hi16(u32 q){ return __builtin_bit_cast(float, q & 0xFFFF0000u); }

// slice buffer base (in shorts)
#define SBUF(sl) ((size_t)(sl)*NNODES*SLF)

// ---------------- int64-vs-int32 edge_index format probe ----------------
__global__ void detect_fmt(const u64* __restrict__ ei64, int* __restrict__ flag){
  u64 v = ei64[threadIdx.x];
  u64 b = __ballot((v >> 32) != 0ull);
  if (threadIdx.x == 0) flag[0] = (b == 0ull) ? 1 : 0;
}

__device__ __forceinline__ int load_dst(const int* ei, int is64, int e){
  return is64 ? ei[2*(NEDGES + e)] : ei[NEDGES + e];
}
__device__ __forceinline__ int load_src(const int* ei, int is64, int e){
  return is64 ? ei[2*e] : ei[e];
}

// ---------------- CSR build ----------------
__global__ void zero_counts(int* counts){
  int i = blockIdx.x*256 + threadIdx.x;
  if (i < NNODES) counts[i] = 0;
}

__global__ void hist_kernel(const int* __restrict__ ei, const int* __restrict__ flag, int* counts){
  int e = blockIdx.x*256 + threadIdx.x;
  if (e < NEDGES){
    int d = load_dst(ei, flag[0], e);
    if ((unsigned)d < NNODES) atomicAdd(&counts[d], 1);
  }
}

__global__ __launch_bounds__(256) void scan1(const int* __restrict__ counts,
                                             int* __restrict__ scanned,
                                             int* __restrict__ partials){
  __shared__ int s[256];
  int t = threadIdx.x, i = blockIdx.x*256 + t;
  int v = (i < NNODES) ? counts[i] : 0;
  s[t] = v; __syncthreads();
  for (int off=1; off<256; off<<=1){
    int a = (t >= off) ? s[t-off] : 0;
    __syncthreads();
    s[t] += a;
    __syncthreads();
  }
  if (i < NNODES) scanned[i] = s[t] - v;
  if (t == 255) partials[blockIdx.x] = s[255];
}

__global__ __launch_bounds__(512) void scan2(int* partials, int G){
  __shared__ int s[512];
  int t = threadIdx.x;
  int v = (t < G) ? partials[t] : 0;
  s[t] = v; __syncthreads();
  for (int off=1; off<512; off<<=1){
    int a = (t >= off) ? s[t-off] : 0;
    __syncthreads();
    s[t] += a;
    __syncthreads();
  }
  if (t < G) partials[t] = s[t] - v;
}

__global__ void scan3(const int* __restrict__ scanned, const int* __restrict__ partials,
                      int* __restrict__ row_ptr, int* __restrict__ cursor){
  int i = blockIdx.x*256 + threadIdx.x;
  if (i < NNODES){
    int v = scanned[i] + partials[i>>8];
    row_ptr[i] = v;
    cursor[i]  = v;
  } else if (i == NNODES){
    row_ptr[NNODES] = NEDGES;
  }
}

// packed meta: bits[16:0]=src (NNODES<2^17), bits[31:17]=weight as sign-less bf16 (exp8+man7)
__global__ void scatter_kernel(const int* __restrict__ ei, const float* __restrict__ ew,
                               const int* __restrict__ flag,
                               int* cursor, u32* __restrict__ meta){
  int e = blockIdx.x*256 + threadIdx.x;
  if (e < NEDGES){
    int is64 = flag[0];
    int s = load_src(ei, is64, e);
    int d = load_dst(ei, is64, e);
    float w = __builtin_nontemporal_load(&ew[e]);
    if ((unsigned)d < NNODES && (unsigned)s < NNODES){
      int pos = atomicAdd(&cursor[d], 1);
      if ((unsigned)pos < NEDGES){
        u32 wb = __builtin_bit_cast(u32, w);
        u32 w15 = ((wb + 0x8000u) >> 16) & 0x7FFFu;   // round-to-nearest, drop sign (w>=0)
        __builtin_nontemporal_store((w15 << 17) | (u32)s, &meta[pos]);
      }
    }
  }
}

// ---------------- weight prep (fp32 -> bf16, transposed to [C][K]) ----------------
__global__ void prep_w(const float* __restrict__ w0, const float* __restrict__ cw,
                       const float* __restrict__ w1,
                       short* __restrict__ w0t, short* __restrict__ cwt, short* __restrict__ w1t){
  int i = blockIdx.x*256 + threadIdx.x;
  const int n0 = NNETS*HF*HF;
  const int n1 = NNETS*NLAYERS*HF*HF;
  const int n2 = NNETS*OUTF*HF;
  if (i < n0){
    int net = i/(HF*HF), r = i%(HF*HF), c = r/HF, k = r%HF;
    w0t[i] = (short)f2bf(w0[(size_t)net*HF*HF + k*HF + c]);
  } else if (i < n0 + n1){
    int j = i - n0;
    int nl = j/(HF*HF), r = j%(HF*HF), c = r/HF, k = r%HF;
    cwt[j] = (short)f2bf(cw[(size_t)nl*HF*HF + k*HF + c]);
  } else if (i < n0 + n1 + n2){
    int j = i - n0 - n1;
    int net = j/(OUTF*HF), r = j%(OUTF*HF), c = r/HF, k = r%HF;
    w1t[j] = (short)f2bf(w1[(size_t)net*HF*OUTF + k*OUTF + c]);
  }
}

// ---------------- input GEMM: h0 = relu(x @ w0 + b0), x0 = h0, all 3 nets, sliced out ----------------
__global__ __launch_bounds__(256) void gemm_in(
    const float* __restrict__ x, const short* __restrict__ w0t, const float* __restrict__ b0,
    short* __restrict__ hs, short* __restrict__ x0s)
{
  __shared__ short As[128*128];
  const int t = threadIdx.x;
  const int rowBase = blockIdx.x * 128;
  #pragma unroll
  for (int it=0; it<8; ++it){
    int r = it*16 + (t>>4);
    int k = (t&15)*8;
    int gr = rowBase + r;
    bf16x8 v = {0,0,0,0,0,0,0,0};
    if (gr < NNODES){
      f32x4 f0 = __builtin_nontemporal_load((const f32x4*)&x[(size_t)gr*128 + k]);
      f32x4 f1 = __builtin_nontemporal_load((const f32x4*)&x[(size_t)gr*128 + k + 4]);
      v[0]=(short)f2bf(f0[0]); v[1]=(short)f2bf(f0[1]); v[2]=(short)f2bf(f0[2]); v[3]=(short)f2bf(f0[3]);
      v[4]=(short)f2bf(f1[0]); v[5]=(short)f2bf(f1[1]); v[6]=(short)f2bf(f1[2]); v[7]=(short)f2bf(f1[3]);
    }
    *(bf16x8*)&As[r*128 + (k ^ ((r&7)<<3))] = v;
  }
  __syncthreads();

  const int wid = t>>6, lane = t&63;
  const int l16 = lane&15, kg = lane>>4;
  for (int net=0; net<NNETS; ++net){
    const short* Wt = w0t + (size_t)net*HF*HF;
    f32x4 acc[2][8];
    #pragma unroll
    for (int mt=0; mt<2; ++mt)
      #pragma unroll
      for (int nt=0; nt<8; ++nt){ acc[mt][nt][0]=0.f; acc[mt][nt][1]=0.f; acc[mt][nt][2]=0.f; acc[mt][nt][3]=0.f; }
    #pragma unroll
    for (int ks=0; ks<4; ++ks){
      int k0 = ks*32 + kg*8;
      bf16x8 a0, a1;
      { int r = wid*32 + l16;      a0 = *(const bf16x8*)&As[r*128 + (k0 ^ ((r&7)<<3))]; }
      { int r = wid*32 + 16 + l16; a1 = *(const bf16x8*)&As[r*128 + (k0 ^ ((r&7)<<3))]; }
      #pragma unroll
      for (int nt=0; nt<8; ++nt){
        bf16x8 b = *(const bf16x8*)&Wt[(size_t)(nt*16 + l16)*128 + k0];
        acc[0][nt] = __builtin_amdgcn_mfma_f32_16x16x32_bf16(a0, b, acc[0][nt], 0, 0, 0);
        acc[1][nt] = __builtin_amdgcn_mfma_f32_16x16x32_bf16(a1, b, acc[1][nt], 0, 0, 0);
      }
    }
    #pragma unroll
    for (int mt=0; mt<2; ++mt){
      #pragma unroll
      for (int nt=0; nt<8; ++nt){
        int g0 = net*128 + nt*16;            // 16-col block start; fully inside one slice
        int sl = g0/SLF, rem = g0%SLF;
        #pragma unroll
        for (int j=0; j<4; ++j){
          int row = rowBase + wid*32 + mt*16 + kg*4 + j;
          if (row < NNODES){
            float v = fmaxf(acc[mt][nt][j] + b0[net*HF + nt*16 + l16], 0.f);
            short bv = (short)f2bf(v);
            size_t idx = SBUF(sl) + (size_t)row*SLF + rem + l16;
            hs [idx] = bv;
            x0s[idx] = bv;
          }
        }
      }
    }
  }
}

// ---------------- mid GEMM: t = 0.9*agg + 0.1*x0 (sliced in); h = relu((1-beta)*t + beta*(t @ cw)) ----------------
__global__ __launch_bounds__(256) void gemm_mid(
    const short* __restrict__ aggs, const short* __restrict__ x0s,
    const short* __restrict__ W, const float beta,
    short* __restrict__ hs)
{
  __shared__ short As[128*128];
  const int t = threadIdx.x;
  const int net = blockIdx.y;
  const int rowBase = blockIdx.x * 128;
  const short* Wt = W + (size_t)net*NLAYERS*HF*HF;

  #pragma unroll
  for (int it=0; it<8; ++it){
    int r = it*16 + (t>>4);
    int k = (t&15)*8;
    int gr = rowBase + r;
    bf16x8 v = {0,0,0,0,0,0,0,0};
    if (gr < NNODES){
      int b8 = net*16 + (t&15);              // global 8-col block
      size_t a = SBUF(b8/6) + (size_t)gr*SLF + (b8%6)*8;
      bf16x8 av = __builtin_nontemporal_load((const bf16x8*)&aggs[a]);
      bf16x8 xv = *(const bf16x8*)&x0s[a];
      #pragma unroll
      for (int j=0; j<8; ++j) v[j] = (short)f2bf(0.9f*bf2f(av[j]) + 0.1f*bf2f(xv[j]));
    }
    *(bf16x8*)&As[r*128 + (k ^ ((r&7)<<3))] = v;
  }
  __syncthreads();

  const int wid = t>>6, lane = t&63;
  const int l16 = lane&15, kg = lane>>4;
  f32x4 acc[2][8];
  #pragma unroll
  for (int mt=0; mt<2; ++mt)
    #pragma unroll
    for (int nt=0; nt<8; ++nt){ acc[mt][nt][0]=0.f; acc[mt][nt][1]=0.f; acc[mt][nt][2]=0.f; acc[mt][nt][3]=0.f; }

  #pragma unroll
  for (int ks=0; ks<4; ++ks){
    int k0 = ks*32 + kg*8;
    bf16x8 a0, a1;
    { int r = wid*32 + l16;      a0 = *(const bf16x8*)&As[r*128 + (k0 ^ ((r&7)<<3))]; }
    { int r = wid*32 + 16 + l16; a1 = *(const bf16x8*)&As[r*128 + (k0 ^ ((r&7)<<3))]; }
    #pragma unroll
    for (int nt=0; nt<8; ++nt){
      bf16x8 b = *(const bf16x8*)&Wt[(size_t)(nt*16 + l16)*128 + k0];
      acc[0][nt] = __builtin_amdgcn_mfma_f32_16x16x32_bf16(a0, b, acc[0][nt], 0, 0, 0);
      acc[1][nt] = __builtin_amdgcn_mfma_f32_16x16x32_bf16(a1, b, acc[1][nt], 0, 0, 0);
    }
  }

  #pragma unroll
  for (int mt=0; mt<2; ++mt){
    #pragma unroll
    for (int nt=0; nt<8; ++nt){
      int g0 = net*128 + nt*16;
      int sl = g0/SLF, rem = g0%SLF;
      #pragma unroll
      for (int j=0; j<4; ++j){
        int rl  = wid*32 + mt*16 + kg*4 + j;
        int row = rowBase + rl;
        int col = nt*16 + l16;
        if (row < NNODES){
          float av = bf2f(As[rl*128 + (col ^ ((rl&7)<<3))]);
          float v = fmaxf((1.f-beta)*av + beta*acc[mt][nt][j], 0.f);
          hs[SBUF(sl) + (size_t)row*SLF + rem + l16] = (short)f2bf(v);
        }
      }
    }
  }
}

// ---------------- output GEMM: logits+log_softmax+ensemble mean (sliced h in) ----------------
__global__ __launch_bounds__(256) void gemm_out(
    const short* __restrict__ hs, const short* __restrict__ w1t, const float* __restrict__ b1,
    float* __restrict__ out)
{
  __shared__ short As[128*128];
  const int t = threadIdx.x;
  const int rowBase = blockIdx.x * 128;
  const int wid = t>>6, lane = t&63;
  const int l16 = lane&15, kg = lane>>4;

  f32x4 sum[2][7];
  #pragma unroll
  for (int mt=0; mt<2; ++mt)
    #pragma unroll
    for (int nt=0; nt<7; ++nt){ sum[mt][nt][0]=0.f; sum[mt][nt][1]=0.f; sum[mt][nt][2]=0.f; sum[mt][nt][3]=0.f; }

  for (int net=0; net<NNETS; ++net){
    __syncthreads();
    #pragma unroll
    for (int it=0; it<8; ++it){
      int r = it*16 + (t>>4);
      int k = (t&15)*8;
      int gr = rowBase + r;
      bf16x8 v = {0,0,0,0,0,0,0,0};
      if (gr < NNODES){
        int b8 = net*16 + (t&15);
        v = *(const bf16x8*)&hs[SBUF(b8/6) + (size_t)gr*SLF + (b8%6)*8];
      }
      *(bf16x8*)&As[r*128 + (k ^ ((r&7)<<3))] = v;
    }
    __syncthreads();

    const short* Wt = w1t + (size_t)net*OUTF*HF;
    f32x4 acc[2][7];
    #pragma unroll
    for (int mt=0; mt<2; ++mt)
      #pragma unroll
      for (int nt=0; nt<7; ++nt){ acc[mt][nt][0]=0.f; acc[mt][nt][1]=0.f; acc[mt][nt][2]=0.f; acc[mt][nt][3]=0.f; }
    #pragma unroll
    for (int ks=0; ks<4; ++ks){
      int k0 = ks*32 + kg*8;
      bf16x8 a0, a1;
      { int r = wid*32 + l16;      a0 = *(const bf16x8*)&As[r*128 + (k0 ^ ((r&7)<<3))]; }
      { int r = wid*32 + 16 + l16; a1 = *(const bf16x8*)&As[r*128 + (k0 ^ ((r&7)<<3))]; }
      #pragma unroll
      for (int nt=0; nt<7; ++nt){
        bf16x8 b = *(const bf16x8*)&Wt[(size_t)(nt*16 + l16)*128 + k0];
        acc[0][nt] = __builtin_amdgcn_mfma_f32_16x16x32_bf16(a0, b, acc[0][nt], 0, 0, 0);
        acc[1][nt] = __builtin_amdgcn_mfma_f32_16x16x32_bf16(a1, b, acc[1][nt], 0, 0, 0);
      }
    }
    #pragma unroll
    for (int mt=0; mt<2; ++mt)
      #pragma unroll
      for (int nt=0; nt<7; ++nt){
        float b = b1[net*OUTF + nt*16 + l16];
        #pragma unroll
        for (int j=0; j<4; ++j) acc[mt][nt][j] += b;
      }
    #pragma unroll
    for (int mt=0; mt<2; ++mt){
      #pragma unroll
      for (int j=0; j<4; ++j){
        float m = -3.4e38f;
        #pragma unroll
        for (int nt=0; nt<7; ++nt) m = fmaxf(m, acc[mt][nt][j]);
        #pragma unroll
        for (int k=1; k<16; k<<=1) m = fmaxf(m, __shfl_xor(m, k));
        float e = 0.f;
        #pragma unroll
        for (int nt=0; nt<7; ++nt) e += expf(acc[mt][nt][j] - m);
        #pragma unroll
        for (int k=1; k<16; k<<=1) e += __shfl_xor(e, k);
        float lse = m + logf(e);
        #pragma unroll
        for (int nt=0; nt<7; ++nt) sum[mt][nt][j] += acc[mt][nt][j] - lse;
      }
    }
  }

  #pragma unroll
  for (int mt=0; mt<2; ++mt){
    #pragma unroll
    for (int nt=0; nt<7; ++nt){
      #pragma unroll
      for (int j=0; j<4; ++j){
        int row = rowBase + wid*32 + mt*16 + kg*4 + j;
        if (row < NNODES)
          __builtin_nontemporal_store(sum[mt][nt][j] * (1.f/3.f),
                                      &out[(size_t)row*OUTF + nt*16 + l16]);
      }
    }
  }
}

// ---------------- sliced SpMM: agg[slice] = A @ h[slice] ----------------
// grid(8, 25000): blockIdx.x = slice = linear%8 -> XCD-pinned slice working set (9.6 MB)
// wave = 1 (dst,slice); 8 edge-slots x 8 feat-lanes; 6 feats (3 dwords) per lane
__global__ __launch_bounds__(256) void spmm3(
    const int* __restrict__ row_ptr, const u32* __restrict__ meta,
    const short* __restrict__ hs, short* __restrict__ aggs)
{
  const int slice = blockIdx.x;
  const int dst   = blockIdx.y*4 + (threadIdx.x>>6);
  const int lane  = threadIdx.x & 63;
  const int slot  = lane >> 3;
  const int fl    = lane & 7;
  const short* hb = hs + SBUF(slice);
  int start = row_ptr[dst], end = row_ptr[dst+1];
  float a[6] = {0.f,0.f,0.f,0.f,0.f,0.f};
  int e = start + slot;
  for (; e + 8 < end; e += 16){
    u32 m0 = __builtin_nontemporal_load(&meta[e]);
    u32 m1 = __builtin_nontemporal_load(&meta[e+8]);
    const short* p0 = hb + (size_t)(m0 & 0x1FFFFu)*SLF + fl*6;
    const short* p1 = hb + (size_t)(m1 & 0x1FFFFu)*SLF + fl*6;
    float w0 = __builtin_bit_cast(float, (m0 >> 17) << 16);
    float w1 = __builtin_bit_cast(float, (m1 >> 17) << 16);
    u32 q00 = *(const u32*)(p0);
    u32 q01 = *(const u32*)(p0+2);
    u32 q02 = *(const u32*)(p0+4);
    u32 q10 = *(const u32*)(p1);
    u32 q11 = *(const u32*)(p1+2);
    u32 q12 = *(const u32*)(p1+4);
    a[0] += w0*lo16(q00) + w1*lo16(q10);
    a[1] += w0*hi16(q00) + w1*hi16(q10);
    a[2] += w0*lo16(q01) + w1*lo16(q11);
    a[3] += w0*hi16(q01) + w1*hi16(q11);
    a[4] += w0*lo16(q02) + w1*lo16(q12);
    a[5] += w0*hi16(q02) + w1*hi16(q12);
  }
  for (; e < end; e += 8){
    u32 m0 = __builtin_nontemporal_load(&meta[e]);
    const short* p0 = hb + (size_t)(m0 & 0x1FFFFu)*SLF + fl*6;
    float w0 = __builtin_bit_cast(float, (m0 >> 17) << 16);
    u32 q00 = *(const u32*)(p0);
    u32 q01 = *(const u32*)(p0+2);
    u32 q02 = *(const u32*)(p0+4);
    a[0] += w0*lo16(q00);
    a[1] += w0*hi16(q00);
    a[2] += w0*lo16(q01);
    a[3] += w0*hi16(q01);
    a[4] += w0*lo16(q02);
    a[5] += w0*hi16(q02);
  }
  #pragma unroll
  for (int j=0; j<6; ++j){
    a[j] += __shfl_xor(a[j], 8);
    a[j] += __shfl_xor(a[j], 16);
    a[j] += __shfl_xor(a[j], 32);
  }
  if (slot == 0){
    short* ob = aggs + SBUF(slice) + (size_t)dst*SLF + fl*6;
    u32 r0 = ((u32)f2bf(a[1]) << 16) | f2bf(a[0]);
    u32 r1 = ((u32)f2bf(a[3]) << 16) | f2bf(a[2]);
    u32 r2 = ((u32)f2bf(a[5]) << 16) | f2bf(a[4]);
    __builtin_nontemporal_store(r0, (u32*)(ob));
    __builtin_nontemporal_store(r1, (u32*)(ob+2));
    __builtin_nontemporal_store(r2, (u32*)(ob+4));
  }
}

extern "C" void kernel_launch(void* const* d_in, const int* in_sizes, int n_in,
                              void* d_out, int out_size, void* d_ws, size_t ws_size,
                              hipStream_t stream){
  const float* x  = (const float*)d_in[0];
  const int*   ei = (const int*)d_in[1];
  const float* ew = (const float*)d_in[2];
  const float* w0 = (const float*)d_in[3];
  const float* b0 = (const float*)d_in[4];
  const float* w1 = (const float*)d_in[5];
  const float* b1 = (const float*)d_in[6];
  const float* cw = (const float*)d_in[7];
  float* out = (float*)d_out;

  char* ws = (char*)d_ws;
  size_t o = 0;
  auto alloc = [&](size_t b){ size_t r = o; o += (b + 255) & ~(size_t)255; return r; };
  int*   flag     = (int*)(ws + alloc(256));
  int*   counts   = (int*)(ws + alloc((size_t)NNODES*4));
  int*   scanned  = (int*)(ws + alloc((size_t)NNODES*4));
  int*   cursor   = (int*)(ws + alloc((size_t)NNODES*4));
  int*   row_ptr  = (int*)(ws + alloc((size_t)(NNODES+1)*4));
  int*   partials = (int*)(ws + alloc(512*4));
  u32*   meta     = (u32*)(ws + alloc((size_t)NEDGES*4));
  short* w0t = (short*)(ws + alloc((size_t)NNETS*HF*HF*2));
  short* cwt = (short*)(ws + alloc((size_t)NNETS*NLAYERS*HF*HF*2));
  short* w1t = (short*)(ws + alloc((size_t)NNETS*OUTF*HF*2));
  short* hs  = (short*)(ws + alloc((size_t)NSL*NNODES*SLF*2));
  short* x0s = (short*)(ws + alloc((size_t)NSL*NNODES*SLF*2));
  short* aggs= (short*)(ws + alloc((size_t)NSL*NNODES*SLF*2));
  (void)ws_size; (void)in_sizes; (void)n_in; (void)out_size;

  detect_fmt    <<<1,   64,  0, stream>>>((const u64*)ei, flag);
  zero_counts   <<<391, 256, 0, stream>>>(counts);
  hist_kernel   <<<6250,256, 0, stream>>>(ei, flag, counts);
  scan1         <<<391, 256, 0, stream>>>(counts, scanned, partials);
  scan2         <<<1,   512, 0, stream>>>(partials, 391);
  scan3         <<<391, 256, 0, stream>>>(scanned, partials, row_ptr, cursor);
  scatter_kernel<<<6250,256, 0, stream>>>(ei, ew, flag, cursor, meta);

  prep_w<<<1128, 256, 0, stream>>>(w0, cw, w1, w0t, cwt, w1t);

  gemm_in<<<782, 256, 0, stream>>>(x, w0t, b0, hs, x0s);
  for (int l=0; l<NLAYERS; ++l){
    float beta = logf(0.5f/(float)(l+1) + 1.0f);
    spmm3<<<dim3(NSL, 25000), 256, 0, stream>>>(row_ptr, meta, hs, aggs);
    gemm_mid<<<dim3(782,3), 256, 0, stream>>>(aggs, x0s, cwt + (size_t)l*HF*HF, beta, hs);
  }
  gemm_out<<<782, 256, 0, stream>>>(hs, w1t, b1, out);
}

// Round 10
// 1245.393 us; speedup vs baseline: 1.6971x; 1.6971x over previous
//
#include <hip/hip_runtime.h>
#include <hip/hip_bf16.h>

#define NNODES 100000
#define NEDGES 1600000
#define INF_   128
#define HF     128
#define OUTF   112
#define NLAYERS 4
#define NNETS  3

typedef __attribute__((ext_vector_type(8))) short bf16x8;
typedef __attribute__((ext_vector_type(8))) unsigned short u16x8;
typedef __attribute__((ext_vector_type(4))) float f32x4;
typedef __attribute__((ext_vector_type(2))) unsigned int u32x2;
typedef unsigned long long u64;
typedef unsigned int u32;

__device__ __forceinline__ float bf2f(short u){
  unsigned x = ((unsigned)(unsigned short)u) << 16;
  return __builtin_bit_cast(float, x);
}
__device__ __forceinline__ unsigned short f2bf(float f){
  unsigned u = __builtin_bit_cast(unsigned, f);
  u += 0x7fffu + ((u >> 16) & 1u);   // RNE
  return (unsigned short)(u >> 16);
}

// hidden-feature permutation: canonical col c -> stored position p
//   p = (c&15)*8 + (c>>4)   (so lane l16's 8 epilogue values are contiguous)
//   inverse: c = (p&7)*16 + (p>>3)

// ---------------- int64-vs-int32 edge_index format probe ----------------
__global__ void detect_fmt(const u64* __restrict__ ei64, int* __restrict__ flag){
  u64 v = ei64[threadIdx.x];
  u64 b = __ballot((v >> 32) != 0ull);
  if (threadIdx.x == 0) flag[0] = (b == 0ull) ? 1 : 0;
}

__device__ __forceinline__ int load_dst(const int* ei, int is64, int e){
  return is64 ? ei[2*(NEDGES + e)] : ei[NEDGES + e];
}
__device__ __forceinline__ int load_src(const int* ei, int is64, int e){
  return is64 ? ei[2*e] : ei[e];
}

// ---------------- CSR build ----------------
__global__ void zero_counts(int* counts){
  int i = blockIdx.x*256 + threadIdx.x;
  if (i < NNODES) counts[i] = 0;
}

__global__ void hist_kernel(const int* __restrict__ ei, const int* __restrict__ flag, int* counts){
  int e = blockIdx.x*256 + threadIdx.x;
  if (e < NEDGES){
    int d = load_dst(ei, flag[0], e);
    if ((unsigned)d < NNODES) atomicAdd(&counts[d], 1);
  }
}

__global__ __launch_bounds__(256) void scan1(const int* __restrict__ counts,
                                             int* __restrict__ scanned,
                                             int* __restrict__ partials){
  __shared__ int s[256];
  int t = threadIdx.x, i = blockIdx.x*256 + t;
  int v = (i < NNODES) ? counts[i] : 0;
  s[t] = v; __syncthreads();
  for (int off=1; off<256; off<<=1){
    int a = (t >= off) ? s[t-off] : 0;
    __syncthreads();
    s[t] += a;
    __syncthreads();
  }
  if (i < NNODES) scanned[i] = s[t] - v;
  if (t == 255) partials[blockIdx.x] = s[255];
}

__global__ __launch_bounds__(512) void scan2(int* partials, int G){
  __shared__ int s[512];
  int t = threadIdx.x;
  int v = (t < G) ? partials[t] : 0;
  s[t] = v; __syncthreads();
  for (int off=1; off<512; off<<=1){
    int a = (t >= off) ? s[t-off] : 0;
    __syncthreads();
    s[t] += a;
    __syncthreads();
  }
  if (t < G) partials[t] = s[t] - v;
}

__global__ void scan3(const int* __restrict__ scanned, const int* __restrict__ partials,
                      int* __restrict__ row_ptr, int* __restrict__ cursor){
  int i = blockIdx.x*256 + threadIdx.x;
  if (i < NNODES){
    int v = scanned[i] + partials[i>>8];
    row_ptr[i] = v;
    cursor[i]  = v;
  } else if (i == NNODES){
    row_ptr[NNODES] = NEDGES;
  }
}

// packed meta: bits[16:0]=src (NNODES<2^17), bits[31:17]=weight as sign-less bf16
__global__ void scatter_kernel(const int* __restrict__ ei, const float* __restrict__ ew,
                               const int* __restrict__ flag,
                               int* cursor, u32* __restrict__ meta){
  int e = blockIdx.x*256 + threadIdx.x;
  if (e < NEDGES){
    int is64 = flag[0];
    int s = load_src(ei, is64, e);
    int d = load_dst(ei, is64, e);
    float w = __builtin_nontemporal_load(&ew[e]);
    if ((unsigned)d < NNODES && (unsigned)s < NNODES){
      int pos = atomicAdd(&cursor[d], 1);
      if ((unsigned)pos < NEDGES){
        u32 wb = __builtin_bit_cast(u32, w);
        u32 w15 = ((wb + 0x8000u) >> 16) & 0x7FFFu;
        __builtin_nontemporal_store((w15 << 17) | (u32)s, &meta[pos]);
      }
    }
  }
}

// ---------------- weight prep (fp32 -> bf16, transposed to [C][K]) ----------------
// cwt/w1t have the K (contraction) index pre-permuted by pi^-1 to match the
// pi-ordered hidden state; w0t stays canonical (x is not permuted).
__global__ void prep_w(const float* __restrict__ w0, const float* __restrict__ cw,
                       const float* __restrict__ w1,
                       short* __restrict__ w0t, short* __restrict__ cwt, short* __restrict__ w1t){
  int i = blockIdx.x*256 + threadIdx.x;
  const int n0 = NNETS*HF*HF;
  const int n1 = NNETS*NLAYERS*HF*HF;
  const int n2 = NNETS*OUTF*HF;
  if (i < n0){
    int net = i/(HF*HF), r = i%(HF*HF), c = r/HF, k = r%HF;
    w0t[i] = (short)f2bf(w0[(size_t)net*HF*HF + k*HF + c]);
  } else if (i < n0 + n1){
    int j = i - n0;
    int nl = j/(HF*HF), r = j%(HF*HF), c = r/HF, kp = r%HF;
    int k = ((kp&7)<<4) | (kp>>3);                 // pi^-1
    cwt[j] = (short)f2bf(cw[(size_t)nl*HF*HF + k*HF + c]);
  } else if (i < n0 + n1 + n2){
    int j = i - n0 - n1;
    int net = j/(OUTF*HF), r = j%(OUTF*HF), c = r/HF, kp = r%HF;
    int k = ((kp&7)<<4) | (kp>>3);                 // pi^-1
    w1t[j] = (short)f2bf(w1[(size_t)net*HF*OUTF + k*OUTF + c]);
  }
}

// ---------------- input GEMM: h0 = relu(x @ w0 + b0); x0 (bf16, pi) + h8/sc (int8, pi) ----------------
__global__ __launch_bounds__(256) void gemm_in(
    const float* __restrict__ x, const short* __restrict__ w0t, const float* __restrict__ b0,
    unsigned char* __restrict__ h8, float* __restrict__ sc, short* __restrict__ x0)
{
  __shared__ short As[128*128];
  const int t = threadIdx.x;
  const int rowBase = blockIdx.x * 128;
  #pragma unroll
  for (int it=0; it<8; ++it){
    int r = it*16 + (t>>4);
    int k = (t&15)*8;
    int gr = rowBase + r;
    bf16x8 v = {0,0,0,0,0,0,0,0};
    if (gr < NNODES){
      f32x4 f0 = __builtin_nontemporal_load((const f32x4*)&x[(size_t)gr*128 + k]);
      f32x4 f1 = __builtin_nontemporal_load((const f32x4*)&x[(size_t)gr*128 + k + 4]);
      v[0]=(short)f2bf(f0[0]); v[1]=(short)f2bf(f0[1]); v[2]=(short)f2bf(f0[2]); v[3]=(short)f2bf(f0[3]);
      v[4]=(short)f2bf(f1[0]); v[5]=(short)f2bf(f1[1]); v[6]=(short)f2bf(f1[2]); v[7]=(short)f2bf(f1[3]);
    }
    *(bf16x8*)&As[r*128 + (k ^ ((r&7)<<3))] = v;
  }
  __syncthreads();

  const int wid = t>>6, lane = t&63;
  const int l16 = lane&15, kg = lane>>4;
  for (int net=0; net<NNETS; ++net){
    const short* Wt = w0t + (size_t)net*HF*HF;
    f32x4 acc[2][8];
    #pragma unroll
    for (int mt=0; mt<2; ++mt)
      #pragma unroll
      for (int nt=0; nt<8; ++nt){ acc[mt][nt][0]=0.f; acc[mt][nt][1]=0.f; acc[mt][nt][2]=0.f; acc[mt][nt][3]=0.f; }
    #pragma unroll
    for (int ks=0; ks<4; ++ks){
      int k0 = ks*32 + kg*8;
      bf16x8 a0, a1;
      { int r = wid*32 + l16;      a0 = *(const bf16x8*)&As[r*128 + (k0 ^ ((r&7)<<3))]; }
      { int r = wid*32 + 16 + l16; a1 = *(const bf16x8*)&As[r*128 + (k0 ^ ((r&7)<<3))]; }
      #pragma unroll
      for (int nt=0; nt<8; ++nt){
        bf16x8 b = *(const bf16x8*)&Wt[(size_t)(nt*16 + l16)*128 + k0];
        acc[0][nt] = __builtin_amdgcn_mfma_f32_16x16x32_bf16(a0, b, acc[0][nt], 0, 0, 0);
        acc[1][nt] = __builtin_amdgcn_mfma_f32_16x16x32_bf16(a1, b, acc[1][nt], 0, 0, 0);
      }
    }
    // epilogue: relu + per-row int8 quant (shfl row-max) + pi-contiguous stores
    #pragma unroll
    for (int mt=0; mt<2; ++mt){
      #pragma unroll
      for (int j=0; j<4; ++j){
        int row = rowBase + wid*32 + mt*16 + kg*4 + j;
        float v[8]; float mx = 0.f;
        #pragma unroll
        for (int nt=0; nt<8; ++nt){
          float f = fmaxf(acc[mt][nt][j] + b0[net*HF + nt*16 + l16], 0.f);
          v[nt] = f; mx = fmaxf(mx, f);
        }
        #pragma unroll
        for (int off=1; off<16; off<<=1) mx = fmaxf(mx, __shfl_xor(mx, off));
        if (row < NNODES){
          u16x8 xo;
          #pragma unroll
          for (int nt=0; nt<8; ++nt) xo[nt] = f2bf(v[nt]);
          *(u16x8*)&x0[((size_t)row*NNETS + net)*128 + l16*8] = xo;
          float inv = (mx > 0.f) ? 255.f/mx : 0.f;
          u32 d0=0, d1=0;
          #pragma unroll
          for (int nt=0; nt<4; ++nt) d0 |= ((u32)(v[nt]*inv + 0.5f)) << (8*nt);
          #pragma unroll
          for (int nt=0; nt<4; ++nt) d1 |= ((u32)(v[4+nt]*inv + 0.5f)) << (8*nt);
          u32x2 pk; pk[0]=d0; pk[1]=d1;
          *(u32x2*)&h8[(size_t)row*384 + net*128 + l16*8] = pk;
          if (l16 == 0) sc[row*4 + net] = mx * (1.f/255.f);
        }
      }
    }
  }
}

// ---------------- mid GEMM: h = relu((1-beta)*t + beta*(t @ cw)) -> h8/sc, net=blockIdx.y ----------------
__global__ __launch_bounds__(256) void gemm_mid(
    const short* __restrict__ tb, const short* __restrict__ W, const float beta,
    unsigned char* __restrict__ h8, float* __restrict__ sc)
{
  __shared__ short As[128*128];
  const int t = threadIdx.x;
  const int net = blockIdx.y;
  const int rowBase = blockIdx.x * 128;
  const short* Wt = W + (size_t)net*NLAYERS*HF*HF;

  #pragma unroll
  for (int it=0; it<8; ++it){
    int r = it*16 + (t>>4);
    int k = (t&15)*8;
    int gr = rowBase + r;
    bf16x8 v = {0,0,0,0,0,0,0,0};
    if (gr < NNODES) v = *(const bf16x8*)&tb[((size_t)gr*NNETS + net)*128 + k];
    *(bf16x8*)&As[r*128 + (k ^ ((r&7)<<3))] = v;
  }
  __syncthreads();

  const int wid = t>>6, lane = t&63;
  const int l16 = lane&15, kg = lane>>4;
  f32x4 acc[2][8];
  #pragma unroll
  for (int mt=0; mt<2; ++mt)
    #pragma unroll
    for (int nt=0; nt<8; ++nt){ acc[mt][nt][0]=0.f; acc[mt][nt][1]=0.f; acc[mt][nt][2]=0.f; acc[mt][nt][3]=0.f; }

  #pragma unroll
  for (int ks=0; ks<4; ++ks){
    int k0 = ks*32 + kg*8;
    bf16x8 a0, a1;
    { int r = wid*32 + l16;      a0 = *(const bf16x8*)&As[r*128 + (k0 ^ ((r&7)<<3))]; }
    { int r = wid*32 + 16 + l16; a1 = *(const bf16x8*)&As[r*128 + (k0 ^ ((r&7)<<3))]; }
    #pragma unroll
    for (int nt=0; nt<8; ++nt){
      bf16x8 b = *(const bf16x8*)&Wt[(size_t)(nt*16 + l16)*128 + k0];
      acc[0][nt] = __builtin_amdgcn_mfma_f32_16x16x32_bf16(a0, b, acc[0][nt], 0, 0, 0);
      acc[1][nt] = __builtin_amdgcn_mfma_f32_16x16x32_bf16(a1, b, acc[1][nt], 0, 0, 0);
    }
  }

  #pragma unroll
  for (int mt=0; mt<2; ++mt){
    #pragma unroll
    for (int j=0; j<4; ++j){
      int rl  = wid*32 + mt*16 + kg*4 + j;
      int row = rowBase + rl;
      float v[8]; float mx = 0.f;
      #pragma unroll
      for (int nt=0; nt<8; ++nt){
        int p = l16*8 + nt;                        // pi(col): t value for this col
        float av = bf2f(As[rl*128 + (p ^ ((rl&7)<<3))]);
        float f = fmaxf((1.f-beta)*av + beta*acc[mt][nt][j], 0.f);
        v[nt] = f; mx = fmaxf(mx, f);
      }
      #pragma unroll
      for (int off=1; off<16; off<<=1) mx = fmaxf(mx, __shfl_xor(mx, off));
      if (row < NNODES){
        float inv = (mx > 0.f) ? 255.f/mx : 0.f;
        u32 d0=0, d1=0;
        #pragma unroll
        for (int nt=0; nt<4; ++nt) d0 |= ((u32)(v[nt]*inv + 0.5f)) << (8*nt);
        #pragma unroll
        for (int nt=0; nt<4; ++nt) d1 |= ((u32)(v[4+nt]*inv + 0.5f)) << (8*nt);
        u32x2 pk; pk[0]=d0; pk[1]=d1;
        *(u32x2*)&h8[(size_t)row*384 + net*128 + l16*8] = pk;
        if (l16 == 0) sc[row*4 + net] = mx * (1.f/255.f);
      }
    }
  }
}

// ---------------- output GEMM: dequant-stage h8, logits+log_softmax+ensemble mean ----------------
__global__ __launch_bounds__(256) void gemm_out(
    const unsigned char* __restrict__ h8, const float* __restrict__ sc,
    const short* __restrict__ w1t, const float* __restrict__ b1,
    float* __restrict__ out)
{
  __shared__ short As[128*128];
  const int t = threadIdx.x;
  const int rowBase = blockIdx.x * 128;
  const int wid = t>>6, lane = t&63;
  const int l16 = lane&15, kg = lane>>4;

  f32x4 sum[2][7];
  #pragma unroll
  for (int mt=0; mt<2; ++mt)
    #pragma unroll
    for (int nt=0; nt<7; ++nt){ sum[mt][nt][0]=0.f; sum[mt][nt][1]=0.f; sum[mt][nt][2]=0.f; sum[mt][nt][3]=0.f; }

  for (int net=0; net<NNETS; ++net){
    __syncthreads();
    #pragma unroll
    for (int it=0; it<8; ++it){
      int r = it*16 + (t>>4);
      int k = (t&15)*8;
      int gr = rowBase + r;
      bf16x8 v = {0,0,0,0,0,0,0,0};
      if (gr < NNODES){
        u32x2 d = *(const u32x2*)&h8[(size_t)gr*384 + net*128 + k];
        float s = sc[gr*4 + net];
        #pragma unroll
        for (int j=0; j<4; ++j) v[j]   = (short)f2bf(s * (float)((d[0]>>(8*j))&0xFF));
        #pragma unroll
        for (int j=0; j<4; ++j) v[4+j] = (short)f2bf(s * (float)((d[1]>>(8*j))&0xFF));
      }
      *(bf16x8*)&As[r*128 + (k ^ ((r&7)<<3))] = v;
    }
    __syncthreads();

    const short* Wt = w1t + (size_t)net*OUTF*HF;
    f32x4 acc[2][7];
    #pragma unroll
    for (int mt=0; mt<2; ++mt)
      #pragma unroll
      for (int nt=0; nt<7; ++nt){ acc[mt][nt][0]=0.f; acc[mt][nt][1]=0.f; acc[mt][nt][2]=0.f; acc[mt][nt][3]=0.f; }
    #pragma unroll
    for (int ks=0; ks<4; ++ks){
      int k0 = ks*32 + kg*8;
      bf16x8 a0, a1;
      { int r = wid*32 + l16;      a0 = *(const bf16x8*)&As[r*128 + (k0 ^ ((r&7)<<3))]; }
      { int r = wid*32 + 16 + l16; a1 = *(const bf16x8*)&As[r*128 + (k0 ^ ((r&7)<<3))]; }
      #pragma unroll
      for (int nt=0; nt<7; ++nt){
        bf16x8 b = *(const bf16x8*)&Wt[(size_t)(nt*16 + l16)*128 + k0];
        acc[0][nt] = __builtin_amdgcn_mfma_f32_16x16x32_bf16(a0, b, acc[0][nt], 0, 0, 0);
        acc[1][nt] = __builtin_amdgcn_mfma_f32_16x16x32_bf16(a1, b, acc[1][nt], 0, 0, 0);
      }
    }
    #pragma unroll
    for (int mt=0; mt<2; ++mt)
      #pragma unroll
      for (int nt=0; nt<7; ++nt){
        float b = b1[net*OUTF + nt*16 + l16];
        #pragma unroll
        for (int j=0; j<4; ++j) acc[mt][nt][j] += b;
      }
    #pragma unroll
    for (int mt=0; mt<2; ++mt){
      #pragma unroll
      for (int j=0; j<4; ++j){
        float m = -3.4e38f;
        #pragma unroll
        for (int nt=0; nt<7; ++nt) m = fmaxf(m, acc[mt][nt][j]);
        #pragma unroll
        for (int k=1; k<16; k<<=1) m = fmaxf(m, __shfl_xor(m, k));
        float e = 0.f;
        #pragma unroll
        for (int nt=0; nt<7; ++nt) e += expf(acc[mt][nt][j] - m);
        #pragma unroll
        for (int k=1; k<16; k<<=1) e += __shfl_xor(e, k);
        float lse = m + logf(e);
        #pragma unroll
        for (int nt=0; nt<7; ++nt) sum[mt][nt][j] += acc[mt][nt][j] - lse;
      }
    }
  }

  #pragma unroll
  for (int mt=0; mt<2; ++mt){
    #pragma unroll
    for (int nt=0; nt<7; ++nt){
      #pragma unroll
      for (int j=0; j<4; ++j){
        int row = rowBase + wid*32 + mt*16 + kg*4 + j;
        if (row < NNODES)
          __builtin_nontemporal_store(sum[mt][nt][j] * (1.f/3.f),
                                      &out[(size_t)row*OUTF + nt*16 + l16]);
      }
    }
  }
}

// ---------------- fused SpMM (all 3 nets, int8 gather): t = 0.9*(A@h) + 0.1*x0 ----------------
// one wave per node; quarter-wave per edge; per edge: 384B int8 row (3 x 128B lines) + 16B scale
__global__ __launch_bounds__(256) void spmm3(
    const int* __restrict__ row_ptr, const u32* __restrict__ meta,
    const unsigned char* __restrict__ h8, const float* __restrict__ sc,
    const short* __restrict__ x0, short* __restrict__ tout)
{
  int node = blockIdx.x*4 + (threadIdx.x>>6);
  int lane = threadIdx.x & 63;
  int q    = lane >> 4;
  int l16  = lane & 15;
  int start = row_ptr[node], end = row_ptr[node+1];
  float acc[3][8] = {{0.f},{0.f},{0.f}};
  int e = start + q;
  for (; e + 4 < end; e += 8){
    u32 m0 = __builtin_nontemporal_load(&meta[e]);
    u32 m1 = __builtin_nontemporal_load(&meta[e+4]);
    u32 s0 = m0 & 0x1FFFFu, s1 = m1 & 0x1FFFFu;
    float w0 = __builtin_bit_cast(float, (m0 >> 17) << 16);
    float w1 = __builtin_bit_cast(float, (m1 >> 17) << 16);
    f32x4 c0 = *(const f32x4*)&sc[s0*4];
    f32x4 c1 = *(const f32x4*)&sc[s1*4];
    const u32* p0 = (const u32*)(h8 + (size_t)s0*384 + l16*8);
    const u32* p1 = (const u32*)(h8 + (size_t)s1*384 + l16*8);
    u32x2 a0 = *(const u32x2*)(p0);
    u32x2 a1 = *(const u32x2*)(p0+32);
    u32x2 a2 = *(const u32x2*)(p0+64);
    u32x2 b0 = *(const u32x2*)(p1);
    u32x2 b1 = *(const u32x2*)(p1+32);
    u32x2 b2 = *(const u32x2*)(p1+64);
    float ws00 = w0*c0[0], ws01 = w0*c0[1], ws02 = w0*c0[2];
    float ws10 = w1*c1[0], ws11 = w1*c1[1], ws12 = w1*c1[2];
    #pragma unroll
    for (int j=0;j<4;++j){
      int sh = 8*j;
      acc[0][j]   += ws00*(float)((a0[0]>>sh)&0xFF) + ws10*(float)((b0[0]>>sh)&0xFF);
      acc[0][j+4] += ws00*(float)((a0[1]>>sh)&0xFF) + ws10*(float)((b0[1]>>sh)&0xFF);
      acc[1][j]   += ws01*(float)((a1[0]>>sh)&0xFF) + ws11*(float)((b1[0]>>sh)&0xFF);
      acc[1][j+4] += ws01*(float)((a1[1]>>sh)&0xFF) + ws11*(float)((b1[1]>>sh)&0xFF);
      acc[2][j]   += ws02*(float)((a2[0]>>sh)&0xFF) + ws12*(float)((b2[0]>>sh)&0xFF);
      acc[2][j+4] += ws02*(float)((a2[1]>>sh)&0xFF) + ws12*(float)((b2[1]>>sh)&0xFF);
    }
  }
  for (; e < end; e += 4){
    u32 m0 = __builtin_nontemporal_load(&meta[e]);
    u32 s0 = m0 & 0x1FFFFu;
    float w0 = __builtin_bit_cast(float, (m0 >> 17) << 16);
    f32x4 c0 = *(const f32x4*)&sc[s0*4];
    const u32* p0 = (const u32*)(h8 + (size_t)s0*384 + l16*8);
    u32x2 a0 = *(const u32x2*)(p0);
    u32x2 a1 = *(const u32x2*)(p0+32);
    u32x2 a2 = *(const u32x2*)(p0+64);
    float ws00 = w0*c0[0], ws01 = w0*c0[1], ws02 = w0*c0[2];
    #pragma unroll
    for (int j=0;j<4;++j){
      int sh = 8*j;
      acc[0][j]   += ws00*(float)((a0[0]>>sh)&0xFF);
      acc[0][j+4] += ws00*(float)((a0[1]>>sh)&0xFF);
      acc[1][j]   += ws01*(float)((a1[0]>>sh)&0xFF);
      acc[1][j+4] += ws01*(float)((a1[1]>>sh)&0xFF);
      acc[2][j]   += ws02*(float)((a2[0]>>sh)&0xFF);
      acc[2][j+4] += ws02*(float)((a2[1]>>sh)&0xFF);
    }
  }
  #pragma unroll
  for (int n=0;n<3;++n)
    #pragma unroll
    for (int j=0;j<8;++j){
      acc[n][j] += __shfl_xor(acc[n][j], 16);
      acc[n][j] += __shfl_xor(acc[n][j], 32);
    }
  if (q < 3){
    size_t base = ((size_t)node*NNETS + q)*128 + l16*8;
    bf16x8 xv = *(const bf16x8*)&x0[base];
    u16x8 o;
    #pragma unroll
    for (int j=0;j<8;++j) o[j] = f2bf(0.9f*acc[q][j] + 0.1f*bf2f(xv[j]));
    __builtin_nontemporal_store(o, (u16x8*)&tout[base]);
  }
}

extern "C" void kernel_launch(void* const* d_in, const int* in_sizes, int n_in,
                              void* d_out, int out_size, void* d_ws, size_t ws_size,
                              hipStream_t stream){
  const float* x  = (const float*)d_in[0];
  const int*   ei = (const int*)d_in[1];
  const float* ew = (const float*)d_in[2];
  const float* w0 = (const float*)d_in[3];
  const float* b0 = (const float*)d_in[4];
  const float* w1 = (const float*)d_in[5];
  const float* b1 = (const float*)d_in[6];
  const float* cw = (const float*)d_in[7];
  float* out = (float*)d_out;

  char* ws = (char*)d_ws;
  size_t o = 0;
  auto alloc = [&](size_t b){ size_t r = o; o += (b + 255) & ~(size_t)255; return r; };
  int*   flag     = (int*)(ws + alloc(256));
  int*   counts   = (int*)(ws + alloc((size_t)NNODES*4));
  int*   scanned  = (int*)(ws + alloc((size_t)NNODES*4));
  int*   cursor   = (int*)(ws + alloc((size_t)NNODES*4));
  int*   row_ptr  = (int*)(ws + alloc((size_t)(NNODES+1)*4));
  int*   partials = (int*)(ws + alloc(512*4));
  u32*   meta     = (u32*)(ws + alloc((size_t)NEDGES*4));
  short* w0t = (short*)(ws + alloc((size_t)NNETS*HF*HF*2));
  short* cwt = (short*)(ws + alloc((size_t)NNETS*NLAYERS*HF*HF*2));
  short* w1t = (short*)(ws + alloc((size_t)NNETS*OUTF*HF*2));
  unsigned char* h8 = (unsigned char*)(ws + alloc((size_t)NNODES*NNETS*128));
  float* sc  = (float*)(ws + alloc((size_t)NNODES*4*4));
  short* x0b = (short*)(ws + alloc((size_t)NNODES*NNETS*HF*2));
  short* tb  = (short*)(ws + alloc((size_t)NNODES*NNETS*HF*2));
  (void)ws_size; (void)in_sizes; (void)n_in; (void)out_size;
  // total ws use ~202 MB (hbuf eliminated; quant fused into GEMM epilogues)

  detect_fmt    <<<1,   64,  0, stream>>>((const u64*)ei, flag);
  zero_counts   <<<391, 256, 0, stream>>>(counts);
  hist_kernel   <<<6250,256, 0, stream>>>(ei, flag, counts);
  scan1         <<<391, 256, 0, stream>>>(counts, scanned, partials);
  scan2         <<<1,   512, 0, stream>>>(partials, 391);
  scan3         <<<391, 256, 0, stream>>>(scanned, partials, row_ptr, cursor);
  scatter_kernel<<<6250,256, 0, stream>>>(ei, ew, flag, cursor, meta);

  prep_w<<<1128, 256, 0, stream>>>(w0, cw, w1, w0t, cwt, w1t);

  gemm_in<<<782, 256, 0, stream>>>(x, w0t, b0, h8, sc, x0b);
  for (int l=0; l<NLAYERS; ++l){
    float beta = logf(0.5f/(float)(l+1) + 1.0f);
    spmm3<<<25000, 256, 0, stream>>>(row_ptr, meta, h8, sc, x0b, tb);
    gemm_mid<<<dim3(782,3), 256, 0, stream>>>(tb, cwt + (size_t)l*HF*HF, beta, h8, sc);
  }
  gemm_out<<<782, 256, 0, stream>>>(h8, sc, w1t, b1, out);
}